// Round 5
// baseline (177.322 us; speedup 1.0000x reference)
//
#include <hip/hip_runtime.h>

#define HIDDEN 128
#define SLOT_H 264  // halves per 32-lane frag slot (256 + 8 pad): 132-word stride → 4-bank rotation, conflict-free

typedef _Float16 f16;
typedef f16 f16x2 __attribute__((ext_vector_type(2)));
typedef f16 f16x8 __attribute__((ext_vector_type(8)));
typedef float f32x16 __attribute__((ext_vector_type(16)));

static __device__ __forceinline__ float fdot2(f16x2 a, f16x2 b, float c) {
    return __builtin_amdgcn_fdot2(a, b, c, false);   // v_dot2_f32_f16
}

// wsh_t[n][k] = Wsym[k][n] = w[k][n] + w[n][k]  (col-major Wsym, fp16) — B operand source
__global__ __launch_bounds__(256) void prep_w(const float* __restrict__ w,
                                              f16* __restrict__ wsh_t) {
    int idx = blockIdx.x * 256 + threadIdx.x;   // 0..16383
    int n = idx >> 7, k = idx & 127;
    wsh_t[idx] = (f16)(w[k * HIDDEN + n] + w[n * HIDDEN + k]);
}

// uh = (f16)(z @ Wsym), zh = (f16)z — fused. MFMA 32x32x16_f16.
// Block = 256 thr / 128 rows; wave owns one 32-row tile x 128 cols (4 accs).
// z: coalesced fp32 float4 reads -> cvt -> (a) coalesced zh f16x8 store,
//    (b) LDS in frag-contiguous layout (conflict-free b128 write+read).
// B: global wsh_t (32 KB, L1/L2-hot).
__global__ __launch_bounds__(256, 3) void gemm_mfma2(const float* __restrict__ z,
                                                     const f16* __restrict__ wsh_t,
                                                     f16* __restrict__ zh,
                                                     f16* __restrict__ uh, int nrows) {
    __shared__ f16 afrag[64 * SLOT_H];   // 64 slots (4 tiles x 8 ks x 2 halves), 33 KB
    int tid = threadIdx.x;
    int row0 = blockIdx.x * 128;
    if (row0 > nrows - 128) row0 = nrows - 128;   // tail overlap: identical writes, benign

    {   // stage: 2048 chunks of 8 halves; thread t handles chunk g = it*256+t
        const float4* zg = (const float4*)(z + (size_t)row0 * HIDDEN);
        f16x8* zhg = (f16x8*)(zh + (size_t)row0 * HIDDEN);
        #pragma unroll
        for (int it = 0; it < 8; ++it) {
            int g = it * 256 + tid;
            float4 v0 = zg[2 * g];          // 32 B/thread contiguous: perfect coalescing
            float4 v1 = zg[2 * g + 1];
            f16x8 h = {(f16)v0.x, (f16)v0.y, (f16)v0.z, (f16)v0.w,
                       (f16)v1.x, (f16)v1.y, (f16)v1.z, (f16)v1.w};
            zhg[g] = h;                      // fused zh emit, coalesced 16 B/thread
            int row = g >> 4, ch = g & 15;   // ch = ks*2 + half
            int slot = (row >> 5) * 16 + ch;
            *(f16x8*)&afrag[slot * SLOT_H + (row & 31) * 8] = h;   // b128, conflict-free
        }
    }
    __syncthreads();

    int wave = tid >> 6, lane = tid & 63;
    int m = lane & 31, half = lane >> 5;

    // B-frag base: B[k][n] = Wsym[k][n] = wsh_t[n*128+k]; lane holds n=m (+32 per tile), k=half*8+j+16ks
    const f16* wb = wsh_t + (size_t)m * HIDDEN + half * 8;

    f32x16 acc0, acc1, acc2, acc3;
    #pragma unroll
    for (int r = 0; r < 16; ++r) { acc0[r] = 0.f; acc1[r] = 0.f; acc2[r] = 0.f; acc3[r] = 0.f; }

    #pragma unroll
    for (int ks = 0; ks < 8; ++ks) {
        f16x8 a = *(const f16x8*)&afrag[(wave * 16 + ks * 2 + half) * SLOT_H + m * 8];
        f16x8 b0 = *(const f16x8*)&wb[ 0 * HIDDEN + 16 * ks];
        f16x8 b1 = *(const f16x8*)&wb[32 * HIDDEN + 16 * ks];
        f16x8 b2 = *(const f16x8*)&wb[64 * HIDDEN + 16 * ks];
        f16x8 b3 = *(const f16x8*)&wb[96 * HIDDEN + 16 * ks];
        acc0 = __builtin_amdgcn_mfma_f32_32x32x16_f16(a, b0, acc0, 0, 0, 0);
        acc1 = __builtin_amdgcn_mfma_f32_32x32x16_f16(a, b1, acc1, 0, 0, 0);
        acc2 = __builtin_amdgcn_mfma_f32_32x32x16_f16(a, b2, acc2, 0, 0, 0);
        acc3 = __builtin_amdgcn_mfma_f32_32x32x16_f16(a, b3, acc3, 0, 0, 0);
    }

    // C/D: col = m (+32/tile), row = (r&3) + 8*(r>>2) + 4*half   [m74/m101]
    f16* ur = uh + (size_t)(row0 + wave * 32) * HIDDEN;
    #pragma unroll
    for (int r = 0; r < 16; ++r) {
        int row = (r & 3) + 8 * (r >> 2) + 4 * half;
        f16* p = ur + (size_t)row * HIDDEN + m;   // 32 lanes x 2 B contiguous per half
        p[0]  = (f16)acc0[r];
        p[32] = (f16)acc1[r];
        p[64] = (f16)acc2[r];
        p[96] = (f16)acc3[r];
    }
}

// out[e] = sigmoid(dot(uh[src], zh[dst])) — 16 lanes/edge, one dwordx4 per side (R2 best: 68.3 µs)
__global__ __launch_bounds__(256) void edge_score16(const f16* __restrict__ uh,
                                                    const f16* __restrict__ zh,
                                                    const int* __restrict__ eidx,
                                                    float* __restrict__ out, int E) {
    int tid = threadIdx.x;
    int g = tid >> 4, t = tid & 15;
    int e = blockIdx.x * 16 + g;
    if (e >= E) return;
    int src = eidx[e];
    int dst = eidx[E + e];
    const float4* a4 = (const float4*)(uh + (size_t)src * HIDDEN);
    const float4* b4 = (const float4*)(zh + (size_t)dst * HIDDEN);
    float4 av = a4[t], bv = b4[t];        // 16 lanes x 16 B = full 256 B row, coalesced
    const f16x2* ap = (const f16x2*)&av;
    const f16x2* bp = (const f16x2*)&bv;
    float s = 0.f;
    #pragma unroll
    for (int i = 0; i < 4; ++i) s = fdot2(ap[i], bp[i], s);
    #pragma unroll
    for (int off = 8; off > 0; off >>= 1) s += __shfl_down(s, off, 16);
    if (t == 0) out[e] = 1.0f / (1.0f + __expf(-s));
}

extern "C" void kernel_launch(void* const* d_in, const int* in_sizes, int n_in,
                              void* d_out, int out_size, void* d_ws, size_t ws_size,
                              hipStream_t stream) {
    const float* z    = (const float*)d_in[0];
    const int*   eidx = (const int*)d_in[1];
    const float* w    = (const float*)d_in[2];
    float* out = (float*)d_out;

    int nrows = in_sizes[0] / HIDDEN;   // 100000
    int E = out_size;                    // 1000000

    f16* wsh_t = (f16*)d_ws;                         // 32 KB
    f16* zh    = wsh_t + HIDDEN * HIDDEN;            // 25.6 MB
    f16* uh    = zh + (size_t)nrows * HIDDEN;        // 25.6 MB

    prep_w<<<(HIDDEN * HIDDEN) / 256, 256, 0, stream>>>(w, wsh_t);
    gemm_mfma2<<<(nrows + 127) / 128, 256, 0, stream>>>(z, wsh_t, zh, uh, nrows);
    edge_score16<<<(E + 15) / 16, 256, 0, stream>>>(uh, zh, eidx, out, E);
}